// Round 10
// baseline (125.398 us; speedup 1.0000x reference)
//
#include <hip/hip_runtime.h>
#include <hip/hip_bf16.h>
#include <stdint.h>

#define SS 2048
#define DD 1024
#define RR 8192   // B*S = 4*2048

typedef _Float16 f16;
typedef _Float16 f16x8 __attribute__((ext_vector_type(8)));
typedef _Float16 f16x4 __attribute__((ext_vector_type(4)));
typedef float    f32x4 __attribute__((ext_vector_type(4)));

// async global->LDS, 16B per lane. lptr must be wave-uniform; HW adds lane*16.
__device__ __forceinline__ void gl_lds16(const f16* g, f16* l) {
  __builtin_amdgcn_global_load_lds((const __attribute__((address_space(1))) void*)g,
                                   (__attribute__((address_space(3))) void*)l,
                                   16, 0, 0);
}

// ---------- K1: fused prologue
//   blocks [0, RR)            : LayerNorm rows -> f16 Xn
//   blocks [RR, RR+512)       : transpose Wq,Wk (f32) -> Wqt,Wkt f16
//   blocks [RR+512, RR+544)   : diag gathers (eos, prior) + zero sup_g/sub_g
__global__ __launch_bounds__(256) void k_pre(const float* __restrict__ x,
                                             const float* __restrict__ gamma,
                                             const float* __restrict__ beta,
                                             f16* __restrict__ xn,
                                             const float* __restrict__ Wq,
                                             const float* __restrict__ Wk,
                                             f16* __restrict__ Wqt,
                                             f16* __restrict__ Wkt,
                                             const int* __restrict__ eos,
                                             const float* __restrict__ prior,
                                             float* __restrict__ sup_g,
                                             float* __restrict__ sub_g,
                                             int* __restrict__ e_sup,
                                             int* __restrict__ e_sub,
                                             float* __restrict__ pr_sup) {
  __shared__ f16 tile[64][72];
  int bidx = blockIdx.x;
  int t = threadIdx.x;
  if (bidx < RR) {
    // ---- LayerNorm row
    int lane = t & 63, w = t >> 6;
    const float* xr = x + (size_t)bidx * DD;
    float4 v = ((const float4*)xr)[t];
    float s  = v.x + v.y + v.z + v.w;
    float ss = v.x*v.x + v.y*v.y + v.z*v.z + v.w*v.w;
#pragma unroll
    for (int off = 32; off > 0; off >>= 1) {
      s  += __shfl_down(s,  off, 64);
      ss += __shfl_down(ss, off, 64);
    }
    float* r0 = (float*)&tile[0][0];
    float* r1 = r0 + 4;
    if (lane == 0) { r0[w] = s; r1[w] = ss; }
    __syncthreads();
    float tot = r0[0]+r0[1]+r0[2]+r0[3];
    float tss = r1[0]+r1[1]+r1[2]+r1[3];
    float mu  = tot * (1.0f/DD);
    float var = tss * (1.0f/DD) - mu*mu;
    float inv = rsqrtf(var + 1e-5f);
    float4 g = ((const float4*)gamma)[t];
    float4 b = ((const float4*)beta)[t];
    f16x4 o;
    o[0] = (f16)((v.x-mu)*inv*g.x + b.x);
    o[1] = (f16)((v.y-mu)*inv*g.y + b.y);
    o[2] = (f16)((v.z-mu)*inv*g.z + b.z);
    o[3] = (f16)((v.w-mu)*inv*g.w + b.w);
    *(f16x4*)(xn + (size_t)bidx*DD + t*4) = o;
  } else if (bidx < RR + 512) {
    // ---- transpose tile
    int bid = bidx - RR;                       // 0..511
    const float* src = (bid & 1) ? Wk : Wq;
    f16* dst = (bid & 1) ? Wkt : Wqt;
    int tb = bid >> 1;
    int r0 = (tb >> 4) << 6, c0 = (tb & 15) << 6;
#pragma unroll
    for (int p = 0; p < 4; ++p) {
      int r = p * 16 + (t >> 4);
      int c = (t & 15) * 4;
      float4 v = *(const float4*)(src + (size_t)(r0 + r) * DD + c0 + c);
      tile[c + 0][r] = (f16)v.x; tile[c + 1][r] = (f16)v.y;
      tile[c + 2][r] = (f16)v.z; tile[c + 3][r] = (f16)v.w;
    }
    __syncthreads();
    int orow = t >> 2, och = (t & 3) * 16;
    f16x8 a = *(const f16x8*)&tile[orow][och];
    f16x8 b = *(const f16x8*)&tile[orow][och + 8];
    f16* o = dst + (size_t)(c0 + orow) * DD + r0 + och;
    *(f16x8*)o = a;
    *(f16x8*)(o + 8) = b;
  } else {
    // ---- gathers + zero accumulators
    int g = bidx - (RR + 512);                 // 0..31
    int u = g * 256 + t;                       // 0..8191
    sup_g[u] = 0.f;
    sub_g[u] = 0.f;
    if (u < 4 * 2047) {
      int b = u / 2047;
      int s = u - b * 2047;                    // 0..2046
      size_t ebase = (size_t)b * SS * SS;
      int bS = b * SS;
      e_sup[bS + s]     = eos[ebase + (size_t)s * SS + s + 1];
      e_sub[bS + s + 1] = eos[ebase + (size_t)(s + 1) * SS + s];
      pr_sup[bS + s]    = prior[ebase + (size_t)s * SS + s + 1];
    }
  }
}

// ---------- K2: NT GEMM template  C = A @ B^T   (f16 in, f32 acc)
// m97 structure: global_load_lds width-16 into LINEAR LDS, 2 barriers/K-step, BK=32, 4 waves.
// FUSE=true: no C write; adjacent-row dots against A (=Xn), atomicAdd into sup_g/sub_g.
// KSPLIT=true: 2 blocks per output tile, each K=512 half; dot is linear in Y so
// partial-acc dots atomically sum to the same result.
template<int BM, int BN, int LOG2NBN, bool FUSE, bool KSPLIT>
__global__ __launch_bounds__(256) void k_gemm_t(const f16* __restrict__ A,
                                                const f16* __restrict__ Bw,
                                                f16* __restrict__ C,
                                                float* __restrict__ sup_g,
                                                float* __restrict__ sub_g) {
  constexpr int K  = 1024;
  constexpr int KW = KSPLIT ? 512 : 1024;      // K-range per block
  constexpr int NC = 1024;
  constexpr int MF = BM / 32;
  constexpr int NF = BN / 32;
  constexpr int IA = BM / 64;
  constexpr int IB = BN / 64;
  constexpr int XST = 136;                     // slab stride (f16): 16B-aligned, 4-way max
  __shared__ f16 As[BM * 32];
  __shared__ f16 Bs[BN * 32];
  __shared__ f16 Xs[FUSE ? 130 * XST : 1];
  int cpx = gridDim.x >> 3;                    // grid divisible by 8
  int bid = (blockIdx.x & 7) * cpx + (blockIdx.x >> 3);
  int ks = 0;
  if constexpr (KSPLIT) { ks = (bid & 1) ? 512 : 0; bid >>= 1; }
  int bm = bid >> LOG2NBN, bn = bid & ((1 << LOG2NBN) - 1);
  int tid = threadIdx.x;
  int lane = tid & 63, w = tid >> 6;
  int wm = w >> 1, wn = w & 1;

  f32x4 acc[MF][NF] = {};

  int srow = w * 16 + (lane >> 2);
  int sch  = lane & 3;
  const f16* AgI[IA];
  const f16* BgI[IB];
  f16* lAI[IA];
  f16* lBI[IB];
#pragma unroll
  for (int i = 0; i < IA; ++i) {
    AgI[i] = A + (size_t)(bm * BM + i * 64 + srow) * K + sch * 8;
    lAI[i] = As + (i * 64 + w * 16) * 32;
  }
#pragma unroll
  for (int i = 0; i < IB; ++i) {
    BgI[i] = Bw + (size_t)(bn * BN + i * 64 + srow) * K + sch * 8;
    lBI[i] = Bs + (i * 64 + w * 16) * 32;
  }

  int rlo = lane & 15, rch = (lane >> 4) * 8;

  for (int kt = ks; kt < ks + KW; kt += 32) {
    __syncthreads();
#pragma unroll
    for (int i = 0; i < IA; ++i) gl_lds16(AgI[i] + kt, lAI[i]);
#pragma unroll
    for (int i = 0; i < IB; ++i) gl_lds16(BgI[i] + kt, lBI[i]);
    __syncthreads();
    f16x8 af[MF], bf[NF];
#pragma unroll
    for (int mi = 0; mi < MF; ++mi)
      af[mi] = *(const f16x8*)(As + (wm * (BM/2) + mi * 16 + rlo) * 32 + rch);
#pragma unroll
    for (int ni = 0; ni < NF; ++ni)
      bf[ni] = *(const f16x8*)(Bs + (wn * (BN/2) + ni * 16 + rlo) * 32 + rch);
#pragma unroll
    for (int mi = 0; mi < MF; ++mi)
#pragma unroll
      for (int ni = 0; ni < NF; ++ni)
        acc[mi][ni] = __builtin_amdgcn_mfma_f32_16x16x32_f16(af[mi], bf[ni], acc[mi][ni], 0, 0, 0);
  }
  int c0 = (lane >> 4) * 4;
  if constexpr (!FUSE) {
#pragma unroll
    for (int mi = 0; mi < MF; ++mi)
#pragma unroll
      for (int ni = 0; ni < NF; ++ni)
#pragma unroll
        for (int r = 0; r < 4; ++r) {
          int row = bm * BM + wm * (BM/2) + mi * 16 + c0 + r;
          int col = bn * BN + wn * (BN/2) + ni * 16 + rlo;
          C[(size_t)row * NC + col] = (f16)acc[mi][ni][r];
        }
  } else {
    // ---- fused adjacent-row dot epilogue.
    // Y[rho][col] lives in acc: rho = bm*128 + wm*64 + mi*16 + c0 + r,
    //                           col = bn*128 + wn*64 + ni*16 + rlo.
    // sup_g[rho-1] += Y[rho]·Xn[rho-1] /32 ; sub_g[rho+1] += Y[rho]·Xn[rho+1] /32.
    // Stage Xn rows [bm*128-1, bm*128+128] x cols [bn*128, +128) into Xs.
    int slabBase = bm * BM - 1;
#pragma unroll
    for (int it = 0; it < 9; ++it) {
      int c = tid + it * 256;                  // chunk id over 130*16
      if (c < 130 * 16) {
        int rI = c >> 4, colc = (c & 15) * 8;
        int gr = slabBase + rI;
        gr = gr < 0 ? 0 : (gr > RR - 1 ? RR - 1 : gr);
        *(f16x8*)(Xs + rI * XST + colc) =
            *(const f16x8*)(A + (size_t)gr * K + bn * BN + colc);
      }
    }
    __syncthreads();
#pragma unroll
    for (int mi = 0; mi < MF; ++mi) {
#pragma unroll
      for (int r = 0; r < 4; ++r) {
        int rloc = wm * (BM/2) + mi * 16 + c0 + r;   // rho - bm*BM
        float su = 0.f, sb = 0.f;
#pragma unroll
        for (int ni = 0; ni < NF; ++ni) {
          float y = acc[mi][ni][r];
          int colL = wn * (BN/2) + ni * 16 + rlo;
          su += y * (float)Xs[rloc * XST + colL];        // row (rho-1)-slabBase = rloc
          sb += y * (float)Xs[(rloc + 2) * XST + colL];  // row (rho+1)-slabBase
        }
#pragma unroll
        for (int m = 1; m < 16; m <<= 1) {
          su += __shfl_xor(su, m, 64);
          sb += __shfl_xor(sb, m, 64);
        }
        if (rlo == 0) {
          int rho = bm * BM + rloc;
          if ((rho & (SS - 1)) != 0)
            atomicAdd(&sup_g[rho - 1], su * 0.03125f);
          if ((rho & (SS - 1)) != SS - 1)
            atomicAdd(&sub_g[rho + 1], sb * 0.03125f);
        }
      }
    }
  }
}

// ---------- K4: per-batch probs + L + inclusive prefix sum P (double), shuffle scan
__global__ __launch_bounds__(1024) void k_scan(const float* __restrict__ sup,
                                               const float* __restrict__ sub,
                                               const int* __restrict__ e_sup,
                                               const int* __restrict__ e_sub,
                                               const float* __restrict__ pr_sup,
                                               float* __restrict__ p_sup,
                                               float* __restrict__ p_sub,
                                               double* __restrict__ P) {
  int b = blockIdx.x, t = threadIdx.x;
  int lane = t & 63, wid = t >> 6;
  int bS = b * SS;
  __shared__ float  psub_sh[SS];
  __shared__ double wsum[16];
  float psup_loc[2];
#pragma unroll
  for (int e = 0; e < 2; ++e) {
    int s = 2*t + e;
    bool supOK = (s < SS-1) && (e_sup[bS + s] != 0);
    bool subOK = (s >= 1)   && (e_sub[bS + s] != 0);
    float ps = 0.f, pb = 0.f;
    if (supOK && subOK) {
      float Av = sup[bS + s], Cv = sub[bS + s];
      float m  = fmaxf(Av, Cv);
      float ea = expf(Av - m), eb = expf(Cv - m);
      float iv = 1.0f / (ea + eb);
      ps = ea * iv; pb = eb * iv;
    } else if (supOK) ps = 1.f;
    else if (subOK)   pb = 1.f;
    p_sup[bS + s] = ps; p_sub[bS + s] = pb;
    psub_sh[s] = pb; psup_loc[e] = ps;
  }
  __syncthreads();
  double L0 = 0.0, L1 = 0.0;
#pragma unroll
  for (int e = 0; e < 2; ++e) {
    int s = 2*t + e;
    double Lv = 0.0;
    if (s < SS-1) {
      float pr = pr_sup[bS + s];
      float vv = sqrtf(psup_loc[e] * psub_sh[s+1] + 1e-9f);
      Lv = (double)logf(pr + (1.f - pr)*vv + 1e-9f);
    }
    if (e == 0) L0 = Lv; else L1 = Lv;
  }
  double pairv = L0 + L1;
  double v = pairv;
#pragma unroll
  for (int off = 1; off < 64; off <<= 1) {
    double u = __shfl_up(v, off, 64);
    if (lane >= off) v += u;
  }
  if (lane == 63) wsum[wid] = v;
  __syncthreads();
  double base = 0.0;
  for (int wI = 0; wI < wid; ++wI) base += wsum[wI];
  double excl = base + v - pairv;
  P[bS + 2*t]     = excl + L0;
  P[bS + 2*t + 1] = excl + L0 + L1;
}

// ---------- K5: elementwise outputs (g_attn, neibor_attn)
__global__ __launch_bounds__(256) void k_out(const float* __restrict__ prior,
                                             const float* __restrict__ p_sup,
                                             const float* __restrict__ p_sub,
                                             const double* __restrict__ P,
                                             float* __restrict__ g_out,
                                             float* __restrict__ n_out) {
  size_t v = (size_t)blockIdx.x * 256 + threadIdx.x;
  int j4   = (int)(v & 511);
  int rowg = (int)(v >> 9);          // 0..16383
  int s = rowg & (SS - 1);
  int b = rowg >> 11;
  size_t base = (size_t)rowg * SS + j4 * 4;
  union F4 { float4 v4; float a[4]; };
  F4 prf; prf.v4 = *(const float4*)(prior + base);
  int bS = b * SS;
  double Ps  = P[bS + s];
  double Ps2 = (s >= 2) ? P[bS + s - 2] : 0.0;
  const float SQ9 = 3.1622776601683795e-5f;   // sqrt(1e-9)
  F4 gv, nv;
#pragma unroll
  for (int e = 0; e < 4; ++e) {
    int j = j4*4 + e;
    float pr = prf.a[e];
    float vv;
    if (j == s + 1)      vv = sqrtf(p_sup[bS+s] * p_sub[bS+s+1] + 1e-9f);
    else if (j == s - 1) vv = sqrtf(p_sub[bS+s] * p_sup[bS+s-1] + 1e-9f);
    else                 vv = SQ9;
    float na = pr + (1.f - pr) * vv;
    nv.a[e] = na;
    float g;
    if (s == j) g = na;
    else if (s > j) {
      double Pj2 = (j >= 2) ? P[bS + j - 2] : 0.0;
      g = expf((float)(Ps - Pj2)) + 1e-9f;
    } else {
      g = expf((float)(P[bS + j] - Ps2)) + 1e-9f;
    }
    gv.a[e] = g;
  }
  *(float4*)(g_out + base) = gv.v4;
  *(float4*)(n_out + base) = nv.v4;
}

extern "C" void kernel_launch(void* const* d_in, const int* in_sizes, int n_in,
                              void* d_out, int out_size, void* d_ws, size_t ws_size,
                              hipStream_t stream) {
  const float* context = (const float*)d_in[0];
  const int*   eos     = (const int*)d_in[1];   // jnp int64 demotes to int32 (no x64)
  const float* prior   = (const float*)d_in[2];
  const float* Wq      = (const float*)d_in[3];
  const float* Wk      = (const float*)d_in[4];
  const float* gamma   = (const float*)d_in[5];
  const float* beta    = (const float*)d_in[6];

  char* ws = (char*)d_ws;
  float*  sup    = (float*)(ws);
  float*  sub    = (float*)(ws + 32768);
  float*  p_sup  = (float*)(ws + 65536);
  float*  p_sub  = (float*)(ws + 98304);
  double* P      = (double*)(ws + 131072);         // 64 KB
  int*    e_sup  = (int*)(ws + 196608);
  int*    e_sub  = (int*)(ws + 229376);
  float*  pr_sup = (float*)(ws + 262144);
  const size_t smallEnd = 294912;

  const size_t XN_BYTES = (size_t)RR * DD * 2;     // 16 MiB
  const size_t WT_BYTES = (size_t)DD * DD * 2;     //  2 MiB each
  const size_t bigNeed  = XN_BYTES + 3 * WT_BYTES; // 22 MiB
  char* big;
  if (ws_size >= smallEnd + bigNeed) big = ws + smallEnd;
  else big = (char*)d_out + ((size_t)out_size * 4 - bigNeed);  // tail of d_out; dead before k_out
  f16* Xn  = (f16*)big;
  f16* Wqt = (f16*)(big + XN_BYTES);
  f16* Wkt = (f16*)(big + XN_BYTES + WT_BYTES);
  f16* Mm  = (f16*)(big + XN_BYTES + 2 * WT_BYTES);

  k_pre<<<RR + 512 + 32, 256, 0, stream>>>(context, gamma, beta, Xn, Wq, Wk, Wqt, Wkt,
                                           eos, prior, sup, sub, e_sup, e_sub, pr_sup);
  // M = Wq^T @ Wk  ==  NT(Wqt, Wkt)
  k_gemm_t<64, 64, 4, false, false><<<256, 256, 0, stream>>>(Wqt, Wkt, Mm, nullptr, nullptr);
  // Y = Xn @ M^T fused with adjacent-row dots -> sup/sub (atomic); K-split x2
  k_gemm_t<128, 128, 3, true, true><<<1024, 256, 0, stream>>>(Xn, Mm, nullptr, sup, sub);
  k_scan<<<4, 1024, 0, stream>>>(sup, sub, e_sup, e_sub, pr_sup, p_sup, p_sub, P);
  float* g_out = (float*)d_out;
  float* n_out = g_out + (size_t)RR * SS;   // 16,777,216 elems each
  k_out<<<16384, 256, 0, stream>>>(prior, p_sup, p_sub, P, g_out, n_out);
}

// Round 11
// 105.088 us; speedup vs baseline: 1.1933x; 1.1933x over previous
//
#include <hip/hip_runtime.h>
#include <hip/hip_bf16.h>
#include <stdint.h>

#define SS 2048
#define DD 1024
#define RR 8192   // B*S = 4*2048

typedef _Float16 f16;
typedef _Float16 f16x8 __attribute__((ext_vector_type(8)));
typedef _Float16 f16x4 __attribute__((ext_vector_type(4)));
typedef float    f32x4 __attribute__((ext_vector_type(4)));

// async global->LDS, 16B per lane. lptr must be wave-uniform; HW adds lane*16.
__device__ __forceinline__ void gl_lds16(const f16* g, f16* l) {
  __builtin_amdgcn_global_load_lds((const __attribute__((address_space(1))) void*)g,
                                   (__attribute__((address_space(3))) void*)l,
                                   16, 0, 0);
}

// ---------- K1: fused prologue
//   blocks [0, RR)            : LayerNorm rows -> f16 Xn
//   blocks [RR, RR+512)       : transpose Wq,Wk (f32) -> Wqt,Wkt f16
//   blocks [RR+512, RR+544)   : diag gathers (eos, prior) + zero sup_g/sub_g
__global__ __launch_bounds__(256) void k_pre(const float* __restrict__ x,
                                             const float* __restrict__ gamma,
                                             const float* __restrict__ beta,
                                             f16* __restrict__ xn,
                                             const float* __restrict__ Wq,
                                             const float* __restrict__ Wk,
                                             f16* __restrict__ Wqt,
                                             f16* __restrict__ Wkt,
                                             const int* __restrict__ eos,
                                             const float* __restrict__ prior,
                                             float* __restrict__ sup_g,
                                             float* __restrict__ sub_g,
                                             int* __restrict__ e_sup,
                                             int* __restrict__ e_sub,
                                             float* __restrict__ pr_sup) {
  __shared__ f16 tile[64][72];
  int bidx = blockIdx.x;
  int t = threadIdx.x;
  if (bidx < RR) {
    // ---- LayerNorm row
    int lane = t & 63, w = t >> 6;
    const float* xr = x + (size_t)bidx * DD;
    float4 v = ((const float4*)xr)[t];
    float s  = v.x + v.y + v.z + v.w;
    float ss = v.x*v.x + v.y*v.y + v.z*v.z + v.w*v.w;
#pragma unroll
    for (int off = 32; off > 0; off >>= 1) {
      s  += __shfl_down(s,  off, 64);
      ss += __shfl_down(ss, off, 64);
    }
    float* r0 = (float*)&tile[0][0];
    float* r1 = r0 + 4;
    if (lane == 0) { r0[w] = s; r1[w] = ss; }
    __syncthreads();
    float tot = r0[0]+r0[1]+r0[2]+r0[3];
    float tss = r1[0]+r1[1]+r1[2]+r1[3];
    float mu  = tot * (1.0f/DD);
    float var = tss * (1.0f/DD) - mu*mu;
    float inv = rsqrtf(var + 1e-5f);
    float4 g = ((const float4*)gamma)[t];
    float4 b = ((const float4*)beta)[t];
    f16x4 o;
    o[0] = (f16)((v.x-mu)*inv*g.x + b.x);
    o[1] = (f16)((v.y-mu)*inv*g.y + b.y);
    o[2] = (f16)((v.z-mu)*inv*g.z + b.z);
    o[3] = (f16)((v.w-mu)*inv*g.w + b.w);
    *(f16x4*)(xn + (size_t)bidx*DD + t*4) = o;
  } else if (bidx < RR + 512) {
    // ---- transpose tile
    int bid = bidx - RR;                       // 0..511
    const float* src = (bid & 1) ? Wk : Wq;
    f16* dst = (bid & 1) ? Wkt : Wqt;
    int tb = bid >> 1;
    int r0 = (tb >> 4) << 6, c0 = (tb & 15) << 6;
#pragma unroll
    for (int p = 0; p < 4; ++p) {
      int r = p * 16 + (t >> 4);
      int c = (t & 15) * 4;
      float4 v = *(const float4*)(src + (size_t)(r0 + r) * DD + c0 + c);
      tile[c + 0][r] = (f16)v.x; tile[c + 1][r] = (f16)v.y;
      tile[c + 2][r] = (f16)v.z; tile[c + 3][r] = (f16)v.w;
    }
    __syncthreads();
    int orow = t >> 2, och = (t & 3) * 16;
    f16x8 a = *(const f16x8*)&tile[orow][och];
    f16x8 b = *(const f16x8*)&tile[orow][och + 8];
    f16* o = dst + (size_t)(c0 + orow) * DD + r0 + och;
    *(f16x8*)o = a;
    *(f16x8*)(o + 8) = b;
  } else {
    // ---- gathers + zero accumulators
    int g = bidx - (RR + 512);                 // 0..31
    int u = g * 256 + t;                       // 0..8191
    sup_g[u] = 0.f;
    sub_g[u] = 0.f;
    if (u < 4 * 2047) {
      int b = u / 2047;
      int s = u - b * 2047;                    // 0..2046
      size_t ebase = (size_t)b * SS * SS;
      int bS = b * SS;
      e_sup[bS + s]     = eos[ebase + (size_t)s * SS + s + 1];
      e_sub[bS + s + 1] = eos[ebase + (size_t)(s + 1) * SS + s];
      pr_sup[bS + s]    = prior[ebase + (size_t)s * SS + s + 1];
    }
  }
}

// ---------- K2: NT GEMM template  C = A @ B^T   (f16 in, f32 acc)
// m97 structure: global_load_lds width-16 into LINEAR LDS, 2 barriers/K-step, BK=32, 4 waves.
// FUSE=true: no C write; instead compute adjacent-row dots against A (=Xn) and
// atomicAdd scaled partials into sup_g/sub_g.
template<int BM, int BN, int LOG2NBN, bool FUSE>
__global__ __launch_bounds__(256) void k_gemm_t(const f16* __restrict__ A,
                                                const f16* __restrict__ Bw,
                                                f16* __restrict__ C,
                                                float* __restrict__ sup_g,
                                                float* __restrict__ sub_g) {
  constexpr int K  = 1024;
  constexpr int NC = 1024;
  constexpr int MF = BM / 32;
  constexpr int NF = BN / 32;
  constexpr int IA = BM / 64;
  constexpr int IB = BN / 64;
  constexpr int XST = 136;                     // slab stride (f16): 16B-aligned, 4-way max
  __shared__ f16 As[BM * 32];
  __shared__ f16 Bs[BN * 32];
  __shared__ f16 Xs[FUSE ? 130 * XST : 1];
  int cpx = gridDim.x >> 3;                    // grid divisible by 8
  int bid = (blockIdx.x & 7) * cpx + (blockIdx.x >> 3);
  int bm = bid >> LOG2NBN, bn = bid & ((1 << LOG2NBN) - 1);
  int tid = threadIdx.x;
  int lane = tid & 63, w = tid >> 6;
  int wm = w >> 1, wn = w & 1;

  f32x4 acc[MF][NF] = {};

  int srow = w * 16 + (lane >> 2);
  int sch  = lane & 3;
  const f16* AgI[IA];
  const f16* BgI[IB];
  f16* lAI[IA];
  f16* lBI[IB];
#pragma unroll
  for (int i = 0; i < IA; ++i) {
    AgI[i] = A + (size_t)(bm * BM + i * 64 + srow) * K + sch * 8;
    lAI[i] = As + (i * 64 + w * 16) * 32;
  }
#pragma unroll
  for (int i = 0; i < IB; ++i) {
    BgI[i] = Bw + (size_t)(bn * BN + i * 64 + srow) * K + sch * 8;
    lBI[i] = Bs + (i * 64 + w * 16) * 32;
  }

  int rlo = lane & 15, rch = (lane >> 4) * 8;

  for (int kt = 0; kt < K; kt += 32) {
    __syncthreads();
#pragma unroll
    for (int i = 0; i < IA; ++i) gl_lds16(AgI[i] + kt, lAI[i]);
#pragma unroll
    for (int i = 0; i < IB; ++i) gl_lds16(BgI[i] + kt, lBI[i]);
    __syncthreads();
    f16x8 af[MF], bf[NF];
#pragma unroll
    for (int mi = 0; mi < MF; ++mi)
      af[mi] = *(const f16x8*)(As + (wm * (BM/2) + mi * 16 + rlo) * 32 + rch);
#pragma unroll
    for (int ni = 0; ni < NF; ++ni)
      bf[ni] = *(const f16x8*)(Bs + (wn * (BN/2) + ni * 16 + rlo) * 32 + rch);
#pragma unroll
    for (int mi = 0; mi < MF; ++mi)
#pragma unroll
      for (int ni = 0; ni < NF; ++ni)
        acc[mi][ni] = __builtin_amdgcn_mfma_f32_16x16x32_f16(af[mi], bf[ni], acc[mi][ni], 0, 0, 0);
  }
  int c0 = (lane >> 4) * 4;
  if constexpr (!FUSE) {
#pragma unroll
    for (int mi = 0; mi < MF; ++mi)
#pragma unroll
      for (int ni = 0; ni < NF; ++ni)
#pragma unroll
        for (int r = 0; r < 4; ++r) {
          int row = bm * BM + wm * (BM/2) + mi * 16 + c0 + r;
          int col = bn * BN + wn * (BN/2) + ni * 16 + rlo;
          C[(size_t)row * NC + col] = (f16)acc[mi][ni][r];
        }
  } else {
    // ---- fused adjacent-row dot epilogue.
    // Y[rho][col] lives in acc: rho = bm*128 + wm*64 + mi*16 + c0 + r,
    //                           col = bn*128 + wn*64 + ni*16 + rlo.
    // sup_g[rho-1] += Y[rho]·Xn[rho-1] /32 ; sub_g[rho+1] += Y[rho]·Xn[rho+1] /32.
    // Stage Xn rows [bm*128-1, bm*128+128] x cols [bn*128, +128) into Xs.
    int slabBase = bm * BM - 1;
#pragma unroll
    for (int it = 0; it < 9; ++it) {
      int c = tid + it * 256;                  // chunk id over 130*16
      if (c < 130 * 16) {
        int rI = c >> 4, colc = (c & 15) * 8;
        int gr = slabBase + rI;
        gr = gr < 0 ? 0 : (gr > RR - 1 ? RR - 1 : gr);
        *(f16x8*)(Xs + rI * XST + colc) =
            *(const f16x8*)(A + (size_t)gr * K + bn * BN + colc);
      }
    }
    __syncthreads();
#pragma unroll
    for (int mi = 0; mi < MF; ++mi) {
#pragma unroll
      for (int r = 0; r < 4; ++r) {
        int rloc = wm * (BM/2) + mi * 16 + c0 + r;   // rho - bm*BM
        float su = 0.f, sb = 0.f;
#pragma unroll
        for (int ni = 0; ni < NF; ++ni) {
          float y = acc[mi][ni][r];
          int colL = wn * (BN/2) + ni * 16 + rlo;
          su += y * (float)Xs[rloc * XST + colL];        // row (rho-1)-slabBase = rloc
          sb += y * (float)Xs[(rloc + 2) * XST + colL];  // row (rho+1)-slabBase
        }
#pragma unroll
        for (int m = 1; m < 16; m <<= 1) {
          su += __shfl_xor(su, m, 64);
          sb += __shfl_xor(sb, m, 64);
        }
        if (rlo == 0) {
          int rho = bm * BM + rloc;
          if ((rho & (SS - 1)) != 0)
            atomicAdd(&sup_g[rho - 1], su * 0.03125f);
          if ((rho & (SS - 1)) != SS - 1)
            atomicAdd(&sub_g[rho + 1], sb * 0.03125f);
        }
      }
    }
  }
}

// ---------- K4: per-batch probs + L + inclusive prefix sum P (double), shuffle scan
__global__ __launch_bounds__(1024) void k_scan(const float* __restrict__ sup,
                                               const float* __restrict__ sub,
                                               const int* __restrict__ e_sup,
                                               const int* __restrict__ e_sub,
                                               const float* __restrict__ pr_sup,
                                               float* __restrict__ p_sup,
                                               float* __restrict__ p_sub,
                                               double* __restrict__ P) {
  int b = blockIdx.x, t = threadIdx.x;
  int lane = t & 63, wid = t >> 6;
  int bS = b * SS;
  __shared__ float  psub_sh[SS];
  __shared__ double wsum[16];
  float psup_loc[2];
#pragma unroll
  for (int e = 0; e < 2; ++e) {
    int s = 2*t + e;
    bool supOK = (s < SS-1) && (e_sup[bS + s] != 0);
    bool subOK = (s >= 1)   && (e_sub[bS + s] != 0);
    float ps = 0.f, pb = 0.f;
    if (supOK && subOK) {
      float Av = sup[bS + s], Cv = sub[bS + s];
      float m  = fmaxf(Av, Cv);
      float ea = expf(Av - m), eb = expf(Cv - m);
      float iv = 1.0f / (ea + eb);
      ps = ea * iv; pb = eb * iv;
    } else if (supOK) ps = 1.f;
    else if (subOK)   pb = 1.f;
    p_sup[bS + s] = ps; p_sub[bS + s] = pb;
    psub_sh[s] = pb; psup_loc[e] = ps;
  }
  __syncthreads();
  double L0 = 0.0, L1 = 0.0;
#pragma unroll
  for (int e = 0; e < 2; ++e) {
    int s = 2*t + e;
    double Lv = 0.0;
    if (s < SS-1) {
      float pr = pr_sup[bS + s];
      float vv = sqrtf(psup_loc[e] * psub_sh[s+1] + 1e-9f);
      Lv = (double)logf(pr + (1.f - pr)*vv + 1e-9f);
    }
    if (e == 0) L0 = Lv; else L1 = Lv;
  }
  double pairv = L0 + L1;
  double v = pairv;
#pragma unroll
  for (int off = 1; off < 64; off <<= 1) {
    double u = __shfl_up(v, off, 64);
    if (lane >= off) v += u;
  }
  if (lane == 63) wsum[wid] = v;
  __syncthreads();
  double base = 0.0;
  for (int wI = 0; wI < wid; ++wI) base += wsum[wI];
  double excl = base + v - pairv;
  P[bS + 2*t]     = excl + L0;
  P[bS + 2*t + 1] = excl + L0 + L1;
}

// ---------- K5: elementwise outputs (g_attn, neibor_attn)
__global__ __launch_bounds__(256) void k_out(const float* __restrict__ prior,
                                             const float* __restrict__ p_sup,
                                             const float* __restrict__ p_sub,
                                             const double* __restrict__ P,
                                             float* __restrict__ g_out,
                                             float* __restrict__ n_out) {
  size_t v = (size_t)blockIdx.x * 256 + threadIdx.x;
  int j4   = (int)(v & 511);
  int rowg = (int)(v >> 9);          // 0..16383
  int s = rowg & (SS - 1);
  int b = rowg >> 11;
  size_t base = (size_t)rowg * SS + j4 * 4;
  union F4 { float4 v4; float a[4]; };
  F4 prf; prf.v4 = *(const float4*)(prior + base);
  int bS = b * SS;
  double Ps  = P[bS + s];
  double Ps2 = (s >= 2) ? P[bS + s - 2] : 0.0;
  const float SQ9 = 3.1622776601683795e-5f;   // sqrt(1e-9)
  F4 gv, nv;
#pragma unroll
  for (int e = 0; e < 4; ++e) {
    int j = j4*4 + e;
    float pr = prf.a[e];
    float vv;
    if (j == s + 1)      vv = sqrtf(p_sup[bS+s] * p_sub[bS+s+1] + 1e-9f);
    else if (j == s - 1) vv = sqrtf(p_sub[bS+s] * p_sup[bS+s-1] + 1e-9f);
    else                 vv = SQ9;
    float na = pr + (1.f - pr) * vv;
    nv.a[e] = na;
    float g;
    if (s == j) g = na;
    else if (s > j) {
      double Pj2 = (j >= 2) ? P[bS + j - 2] : 0.0;
      g = expf((float)(Ps - Pj2)) + 1e-9f;
    } else {
      g = expf((float)(P[bS + j] - Ps2)) + 1e-9f;
    }
    gv.a[e] = g;
  }
  *(float4*)(g_out + base) = gv.v4;
  *(float4*)(n_out + base) = nv.v4;
}

extern "C" void kernel_launch(void* const* d_in, const int* in_sizes, int n_in,
                              void* d_out, int out_size, void* d_ws, size_t ws_size,
                              hipStream_t stream) {
  const float* context = (const float*)d_in[0];
  const int*   eos     = (const int*)d_in[1];   // jnp int64 demotes to int32 (no x64)
  const float* prior   = (const float*)d_in[2];
  const float* Wq      = (const float*)d_in[3];
  const float* Wk      = (const float*)d_in[4];
  const float* gamma   = (const float*)d_in[5];
  const float* beta    = (const float*)d_in[6];

  char* ws = (char*)d_ws;
  float*  sup    = (float*)(ws);
  float*  sub    = (float*)(ws + 32768);
  float*  p_sup  = (float*)(ws + 65536);
  float*  p_sub  = (float*)(ws + 98304);
  double* P      = (double*)(ws + 131072);         // 64 KB
  int*    e_sup  = (int*)(ws + 196608);
  int*    e_sub  = (int*)(ws + 229376);
  float*  pr_sup = (float*)(ws + 262144);
  const size_t smallEnd = 294912;

  const size_t XN_BYTES = (size_t)RR * DD * 2;     // 16 MiB
  const size_t WT_BYTES = (size_t)DD * DD * 2;     //  2 MiB each
  const size_t bigNeed  = XN_BYTES + 3 * WT_BYTES; // 22 MiB
  char* big;
  if (ws_size >= smallEnd + bigNeed) big = ws + smallEnd;
  else big = (char*)d_out + ((size_t)out_size * 4 - bigNeed);  // tail of d_out; dead before k_out
  f16* Xn  = (f16*)big;
  f16* Wqt = (f16*)(big + XN_BYTES);
  f16* Wkt = (f16*)(big + XN_BYTES + WT_BYTES);
  f16* Mm  = (f16*)(big + XN_BYTES + 2 * WT_BYTES);

  k_pre<<<RR + 512 + 32, 256, 0, stream>>>(context, gamma, beta, Xn, Wq, Wk, Wqt, Wkt,
                                           eos, prior, sup, sub, e_sup, e_sub, pr_sup);
  // M = Wq^T @ Wk  ==  NT(Wqt, Wkt)
  k_gemm_t<64, 64, 4, false><<<256, 256, 0, stream>>>(Wqt, Wkt, Mm, nullptr, nullptr);
  // Y = Xn @ M^T fused with adjacent-row dots -> sup/sub (atomic)
  k_gemm_t<128, 128, 3, true><<<512, 256, 0, stream>>>(Xn, Mm, nullptr, sup, sub);
  k_scan<<<4, 1024, 0, stream>>>(sup, sub, e_sup, e_sub, pr_sup, p_sup, p_sub, P);
  float* g_out = (float*)d_out;
  float* n_out = g_out + (size_t)RR * SS;   // 16,777,216 elems each
  k_out<<<16384, 256, 0, stream>>>(prior, p_sup, p_sub, P, g_out, n_out);
}